// Round 6
// baseline (465.525 us; speedup 1.0000x reference)
//
#include <hip/hip_runtime.h>
#include <hip/hip_bf16.h>
#include <math.h>

#define DIMN   1024
#define HEADS  16
#define DHEAD  64
#define CTXD   768
#define FFH    4096
#define NTOK   4096
#define SEQ    2048
#define NCTX   77
#define CTOK   154

typedef unsigned short u16;
typedef __bf16 bf16x8 __attribute__((ext_vector_type(8)));
typedef float  f32x4  __attribute__((ext_vector_type(4)));

__device__ __forceinline__ u16 f2bf(float f) {
  union { float f; unsigned u; } c; c.f = f;
  unsigned r = c.u + 0x7FFFu + ((c.u >> 16) & 1u);
  return (u16)(r >> 16);
}
__device__ __forceinline__ float bf2f(u16 h) {
  union { unsigned u; float f; } c; c.u = ((unsigned)h) << 16; return c.f;
}

__device__ __forceinline__ void gload16(const void* g, void* l) {
  __builtin_amdgcn_global_load_lds(
      (__attribute__((address_space(1))) void*)(void*)(g),
      (__attribute__((address_space(3))) void*)(l), 16, 0, 0);
}

__device__ __forceinline__ f32x4 mfma16(bf16x8 a, bf16x8 b, f32x4 c) {
  return __builtin_amdgcn_mfma_f32_16x16x32_bf16(a, b, c, 0, 0, 0);
}

// ---------------- batched weight convert+transpose: W[K][N] f32 -> WT[N][K] bf16
struct WBatch { const float* s[6]; u16* d[6]; };

template<int NB>
__global__ __launch_bounds__(256)
void wconvB_k(WBatch wb, int K, int N)
{
  __shared__ u16 t[64][65];
  const float* __restrict__ W  = wb.s[blockIdx.z];
  u16* __restrict__       WT   = wb.d[blockIdx.z];
  int n0 = blockIdx.x * 64, k0 = blockIdx.y * 64;
  int tid = threadIdx.x;
  int rr = tid >> 4, cc = tid & 15;
#pragma unroll
  for (int i = 0; i < 4; ++i) {
    int kr = rr + i * 16;
    const float4 v = *(const float4*)&W[(size_t)(k0 + kr) * N + n0 + cc * 4];
    t[kr][cc*4+0] = f2bf(v.x); t[kr][cc*4+1] = f2bf(v.y);
    t[kr][cc*4+2] = f2bf(v.z); t[kr][cc*4+3] = f2bf(v.w);
  }
  __syncthreads();
#pragma unroll
  for (int i = 0; i < 4; ++i) {
    int nr = rr + i * 16;
    int r0 = cc * 4;
    ushort4 o;
    o.x = t[r0+0][nr]; o.y = t[r0+1][nr]; o.z = t[r0+2][nr]; o.w = t[r0+3][nr];
    *(ushort4*)&WT[(size_t)(n0 + nr) * K + k0 + r0] = o;
  }
}

__global__ __launch_bounds__(256)
void wconv_k(const float* __restrict__ W, u16* __restrict__ WT, int K, int N)
{
  __shared__ u16 t[64][65];
  int n0 = blockIdx.x * 64, k0 = blockIdx.y * 64;
  int tid = threadIdx.x;
  int rr = tid >> 4, cc = tid & 15;
#pragma unroll
  for (int i = 0; i < 4; ++i) {
    int kr = rr + i * 16;
    const float4 v = *(const float4*)&W[(size_t)(k0 + kr) * N + n0 + cc * 4];
    t[kr][cc*4+0] = f2bf(v.x); t[kr][cc*4+1] = f2bf(v.y);
    t[kr][cc*4+2] = f2bf(v.z); t[kr][cc*4+3] = f2bf(v.w);
  }
  __syncthreads();
#pragma unroll
  for (int i = 0; i < 4; ++i) {
    int nr = rr + i * 16;
    int r0 = cc * 4;
    ushort4 o;
    o.x = t[r0+0][nr]; o.y = t[r0+1][nr]; o.z = t[r0+2][nr]; o.w = t[r0+3][nr];
    *(ushort4*)&WT[(size_t)(n0 + nr) * K + k0 + r0] = o;
  }
}

// ---------------- f32 -> bf16 elementwise (context)
__global__ void cconv_k(const float* __restrict__ c, u16* __restrict__ o, int n)
{
  int i = blockIdx.x * 256 + threadIdx.x;
  if (i < n) o[i] = f2bf(c[i]);
}

// ---------------- LayerNorm: f32 row[1024] -> bf16
__global__ __launch_bounds__(256)
void ln_k(const float* __restrict__ x, const float* __restrict__ gm,
          const float* __restrict__ bt, u16* __restrict__ o)
{
  int row = blockIdx.x;
  int tid = threadIdx.x;
  const float4 v = *(const float4*)&x[(size_t)row * DIMN + tid * 4];
  float s = v.x + v.y + v.z + v.w;
  float q = v.x*v.x + v.y*v.y + v.z*v.z + v.w*v.w;
#pragma unroll
  for (int off = 32; off; off >>= 1) { s += __shfl_xor(s, off); q += __shfl_xor(q, off); }
  __shared__ float ss[4], qq[4];
  int wave = tid >> 6;
  if ((tid & 63) == 0) { ss[wave] = s; qq[wave] = q; }
  __syncthreads();
  s = ss[0] + ss[1] + ss[2] + ss[3];
  q = qq[0] + qq[1] + qq[2] + qq[3];
  float mu = s * (1.0f / DIMN);
  float var = q * (1.0f / DIMN) - mu * mu;
  float rs = rsqrtf(var + 1e-5f);
  const float4 gv = *(const float4*)&gm[tid * 4];
  const float4 bv = *(const float4*)&bt[tid * 4];
  ushort4 r;
  r.x = f2bf((v.x - mu) * rs * gv.x + bv.x);
  r.y = f2bf((v.y - mu) * rs * gv.y + bv.y);
  r.z = f2bf((v.z - mu) * rs * gv.z + bv.z);
  r.w = f2bf((v.w - mu) * rs * gv.w + bv.w);
  *(ushort4*)&o[(size_t)row * DIMN + tid * 4] = r;
}

// ---------------- GEMM v4: 512 threads, 8 waves, 3-buffer 2-deep prefetch
// A[M][K] bf16 row-major, Bt[N][K] bf16
// MODE 0: out bf16 = acc + bias
// MODE 2: out f32 = acc + bias + resid
// MODE 3: vt store (kv-permuted within 64-granule to match attn P layout)
// MODE 4: QKV fused: colgrp 0->obf (q), 1->ob2 (k), 2->ob3 (vt store)
// MODE 5: KV fused:  colgrp 0->obf (k), 1->ob3 (vt store)
template<int MODE>
__global__ __launch_bounds__(512, 4)
void gemm_k(const u16* __restrict__ A, const u16* __restrict__ Bt,
            int M, int N, int K,
            const float* __restrict__ bias, const float* __restrict__ resid,
            u16* __restrict__ obf, float* __restrict__ of32,
            int seq, int vstride,
            u16* __restrict__ ob2, u16* __restrict__ ob3)
{
  __shared__ __align__(16) u16 As[3][128 * 32];
  __shared__ __align__(16) u16 Bs[3][128 * 32];
  const int tid = threadIdx.x;
  const int lane = tid & 63, wave = tid >> 6;
  const int wr = wave >> 1, wc = wave & 1;          // 4 x 2 wave grid
  const int g = lane >> 4, r16 = lane & 15;
  const int m0 = blockIdx.x * 128, n0 = blockIdx.y * 128;

  f32x4 acc[2][4] = {};

  const int srow = tid >> 2;          // 0..127
  const int sch  = tid & 3;           // 0..3
  const int schs = sch ^ ((srow >> 1) & 3);
  const int arow = (m0 + srow > M - 1) ? (M - 1) : (m0 + srow);
  const size_t abase = (size_t)arow * K + schs * 8;
  const size_t bbase = (size_t)(n0 + srow) * K + schs * 8;

  auto stage = [&](int buf, int kt) {
    gload16(A  + abase + kt, &As[buf][tid * 8]);
    gload16(Bt + bbase + kt, &Bs[buf][tid * 8]);
  };

  const int nkt = K >> 5;
  stage(0, 0);
  if (nkt > 1) stage(1, 32);

  int cur = 0;
  for (int t = 0; t < nkt; ++t) {
    if (t + 1 < nkt) {
      asm volatile("s_waitcnt vmcnt(2)" ::: "memory");   // stage(t) landed
    } else {
      asm volatile("s_waitcnt vmcnt(0)" ::: "memory");
    }
    __builtin_amdgcn_s_barrier();                        // B1

    bf16x8 af[2], bfr[4];
#pragma unroll
    for (int mi = 0; mi < 2; ++mi) {
      int r = wr * 32 + mi * 16 + r16;
      int cph = g ^ ((r >> 1) & 3);
      af[mi] = *(const bf16x8*)&As[cur][(r * 4 + cph) * 8];
    }
#pragma unroll
    for (int ni = 0; ni < 4; ++ni) {
      int r = wc * 64 + ni * 16 + r16;
      int cph = g ^ ((r >> 1) & 3);
      bfr[ni] = *(const bf16x8*)&Bs[cur][(r * 4 + cph) * 8];
    }
    __builtin_amdgcn_s_setprio(1);
#pragma unroll
    for (int mi = 0; mi < 2; ++mi)
#pragma unroll
      for (int ni = 0; ni < 4; ++ni)
        acc[mi][ni] = mfma16(af[mi], bfr[ni], acc[mi][ni]);
    __builtin_amdgcn_s_setprio(0);

    __builtin_amdgcn_s_barrier();                        // B2 (WAR)

    if (t + 2 < nkt) {
      const int nb = (cur == 0) ? 2 : cur - 1;           // (t+2) % 3
      stage(nb, (t + 2) << 5);
    }
    cur = (cur == 2) ? 0 : cur + 1;
  }

  const int grp = n0 >> 10;           // column group for fused modes
#pragma unroll
  for (int ni = 0; ni < 4; ++ni) {
    int col = n0 + wc * 64 + ni * 16 + r16;
    float bv = 0.0f;
    if constexpr (MODE == 0 || MODE == 2) bv = bias ? bias[col] : 0.0f;
    const int c1 = col & 1023;
#pragma unroll
    for (int mi = 0; mi < 2; ++mi) {
      f32x4 c = acc[mi][ni];
#pragma unroll
      for (int rg = 0; rg < 4; ++rg) {
        int row = m0 + wr * 32 + mi * 16 + g * 4 + rg;
        if (row < M) {
          float v = c[rg] + bv;
          if constexpr (MODE == 0) {
            obf[(size_t)row * N + col] = f2bf(v);
          } else if constexpr (MODE == 2) {
            size_t o = (size_t)row * N + col;
            of32[o] = v + resid[o];
          } else if constexpr (MODE == 3) {
            int b = row / seq, srow_ = row - b * seq;
            int jg = srow_ >> 6, j = srow_ & 63;
            int pos = jg * 64 + ((j & 15) << 2) + (j >> 4);
            obf[((size_t)b * HEADS * DHEAD + c1) * vstride + pos] = f2bf(v);
          } else if constexpr (MODE == 4) {
            if (grp == 0) {
              obf[(size_t)row * 1024 + c1] = f2bf(v);
            } else if (grp == 1) {
              ob2[(size_t)row * 1024 + c1] = f2bf(v);
            } else {
              int b = row / seq, srow_ = row - b * seq;
              int jg = srow_ >> 6, j = srow_ & 63;
              int pos = jg * 64 + ((j & 15) << 2) + (j >> 4);
              ob3[((size_t)b * HEADS * DHEAD + c1) * vstride + pos] = f2bf(v);
            }
          } else {  // MODE 5
            if (grp == 0) {
              obf[(size_t)row * 1024 + c1] = f2bf(v);
            } else {
              int b = row / seq, srow_ = row - b * seq;
              int jg = srow_ >> 6, j = srow_ & 63;
              int pos = jg * 64 + ((j & 15) << 2) + (j >> 4);
              ob3[((size_t)b * HEADS * DHEAD + c1) * vstride + pos] = f2bf(v);
            }
          }
        }
      }
    }
  }
}

// ---------------- fused GEGLU GEMM: out = (A@B1 + ba) * gelu(A@B2 + bg)
__global__ __launch_bounds__(512, 2)
void geglu_k(const u16* __restrict__ A, const u16* __restrict__ B1t,
             const u16* __restrict__ B2t,
             const float* __restrict__ ba, const float* __restrict__ bg,
             u16* __restrict__ out, int M, int N)
{
  __shared__ __align__(16) u16 As[3][128 * 32];
  __shared__ __align__(16) u16 B1s[3][128 * 32];
  __shared__ __align__(16) u16 B2s[3][128 * 32];
  const int tid = threadIdx.x;
  const int lane = tid & 63, wave = tid >> 6;
  const int wr = wave >> 1, wc = wave & 1;
  const int g = lane >> 4, r16 = lane & 15;
  const int m0 = blockIdx.x * 128, n0 = blockIdx.y * 128;
  const int K = 1024;

  f32x4 acca[2][4] = {}, accg[2][4] = {};

  const int srow = tid >> 2;
  const int sch  = tid & 3;
  const int schs = sch ^ ((srow >> 1) & 3);
  const size_t abase = (size_t)(m0 + srow) * K + schs * 8;
  const size_t bbase = (size_t)(n0 + srow) * K + schs * 8;

  auto stage = [&](int buf, int kt) {
    gload16(A   + abase + kt, &As[buf][tid * 8]);
    gload16(B1t + bbase + kt, &B1s[buf][tid * 8]);
    gload16(B2t + bbase + kt, &B2s[buf][tid * 8]);
  };

  const int nkt = K >> 5;
  stage(0, 0);
  stage(1, 32);

  int cur = 0;
  for (int t = 0; t < nkt; ++t) {
    if (t + 1 < nkt) {
      asm volatile("s_waitcnt vmcnt(3)" ::: "memory");
    } else {
      asm volatile("s_waitcnt vmcnt(0)" ::: "memory");
    }
    __builtin_amdgcn_s_barrier();                        // B1

    bf16x8 af[2], b1f[4], b2f[4];
#pragma unroll
    for (int mi = 0; mi < 2; ++mi) {
      int r = wr * 32 + mi * 16 + r16;
      int cph = g ^ ((r >> 1) & 3);
      af[mi] = *(const bf16x8*)&As[cur][(r * 4 + cph) * 8];
    }
#pragma unroll
    for (int ni = 0; ni < 4; ++ni) {
      int r = wc * 64 + ni * 16 + r16;
      int cph = g ^ ((r >> 1) & 3);
      b1f[ni] = *(const bf16x8*)&B1s[cur][(r * 4 + cph) * 8];
      b2f[ni] = *(const bf16x8*)&B2s[cur][(r * 4 + cph) * 8];
    }
    __builtin_amdgcn_s_setprio(1);
#pragma unroll
    for (int mi = 0; mi < 2; ++mi)
#pragma unroll
      for (int ni = 0; ni < 4; ++ni) {
        acca[mi][ni] = mfma16(af[mi], b1f[ni], acca[mi][ni]);
        accg[mi][ni] = mfma16(af[mi], b2f[ni], accg[mi][ni]);
      }
    __builtin_amdgcn_s_setprio(0);

    __builtin_amdgcn_s_barrier();                        // B2

    if (t + 2 < nkt) {
      const int nb = (cur == 0) ? 2 : cur - 1;
      stage(nb, (t + 2) << 5);
    }
    cur = (cur == 2) ? 0 : cur + 1;
  }

#pragma unroll
  for (int ni = 0; ni < 4; ++ni) {
    int col = n0 + wc * 64 + ni * 16 + r16;
    float bva = ba[col], bvg = bg[col];
#pragma unroll
    for (int mi = 0; mi < 2; ++mi) {
#pragma unroll
      for (int rg = 0; rg < 4; ++rg) {
        int row = m0 + wr * 32 + mi * 16 + g * 4 + rg;
        float a  = acca[mi][ni][rg] + bva;
        float gt = accg[mi][ni][rg] + bvg;
        float gl = 0.5f * gt * (1.0f + erff(gt * 0.70710678f));
        out[(size_t)row * N + col] = f2bf(a * gl);
      }
    }
  }
}

// ---------------- flash attention v4 (counted vmcnt + raw barriers)
__global__ __launch_bounds__(256)
void attn_k(const u16* __restrict__ q, const u16* __restrict__ k,
            const u16* __restrict__ vt, u16* __restrict__ o,
            int kvlen, int seqk, int vstride)
{
  __shared__ __align__(16) u16 Ks[2][64 * 64];
  __shared__ __align__(16) u16 Vs[2][64 * 64];
  __shared__ __align__(16) u16 Ps[4][32 * 72];
  const int tid = threadIdx.x, lane = tid & 63, wave = tid >> 6;
  const int g = lane >> 4, r16 = lane & 15;
  const int bh = blockIdx.y;
  const int b = bh >> 4, h = bh & 15;
  const int q0 = blockIdx.x * 128 + wave * 32;
  const float C = 0.18033688f;   // log2(e)/8

  bf16x8 aq[2][2];
#pragma unroll
  for (int qs = 0; qs < 2; ++qs) {
    const size_t qoff = (size_t)(b * SEQ + q0 + qs * 16 + r16) * DIMN + h * DHEAD;
#pragma unroll
    for (int kc = 0; kc < 2; ++kc)
      aq[qs][kc] = *(const bf16x8*)&q[qoff + kc * 32 + g * 8];
  }
  // consume Q regs now so the compiler's waitcnt lands HERE, not inside the loop
  asm volatile("" :: "v"(aq[0][0]), "v"(aq[0][1]), "v"(aq[1][0]), "v"(aq[1][1]));

  f32x4 oacc[2][4] = {};
  float mi[2][4], li[2][4];
#pragma unroll
  for (int qs = 0; qs < 2; ++qs)
#pragma unroll
    for (int rg = 0; rg < 4; ++rg) { mi[qs][rg] = -3e38f; li[qs][rg] = 0.f; }

  const size_t vtbase = (size_t)(b * HEADS + h) * DHEAD * vstride;
  const size_t kbase  = (size_t)b * seqk * DIMN + h * DHEAD;
  const int nkv = (kvlen + 63) >> 6;

  auto stage = [&](int buf, int kv0) {
#pragma unroll
    for (int i = 0; i < 2; ++i) {
      const int c = tid + i * 256;
      const int row = c >> 3, ch = c & 7;
      const int chs = ch ^ (row & 7);
      int kr = kv0 + row; if (kr > kvlen - 1) kr = kvlen - 1;
      gload16(k + kbase + (size_t)kr * DIMN + chs * 8, &Ks[buf][c * 8]);
    }
#pragma unroll
    for (int i = 0; i < 2; ++i) {
      const int c = tid + i * 256;
      const int row = c >> 3, ch = c & 7;
      const int chs = ch ^ (row & 7);
      gload16(vt + vtbase + (size_t)row * vstride + kv0 + chs * 8, &Vs[buf][c * 8]);
    }
  };

  stage(0, 0);

  for (int kvb = 0; kvb < nkv; ++kvb) {
    const int kv0 = kvb * 64;
    const int cur = kvb & 1;
    if (kvb + 1 < nkv) {
      stage(cur ^ 1, kv0 + 64);
      asm volatile("s_waitcnt vmcnt(4)" ::: "memory");
    } else {
      asm volatile("s_waitcnt vmcnt(0)" ::: "memory");
    }
    __builtin_amdgcn_s_barrier();                        // B1

    // ---- QK^T: 16 MFMA
    f32x4 sa[2][4];
#pragma unroll
    for (int qs = 0; qs < 2; ++qs)
#pragma unroll
      for (int st = 0; st < 4; ++st) sa[qs][st] = (f32x4){0.f, 0.f, 0.f, 0.f};
    __builtin_amdgcn_s_setprio(1);
#pragma unroll
    for (int st = 0; st < 4; ++st) {
      const int kvr = st * 16 + r16;
#pragma unroll
      for (int kc = 0; kc < 2; ++kc) {
        const int chs = (kc * 4 + g) ^ (kvr & 7);
        const bf16x8 kf = *(const bf16x8*)&Ks[cur][kvr * 64 + chs * 8];
        sa[0][st] = mfma16(aq[0][kc], kf, sa[0][st]);
        sa[1][st] = mfma16(aq[1][kc], kf, sa[1][st]);
      }
    }
    __builtin_amdgcn_s_setprio(0);

    // ---- tail mask (cross-attn last tile only)
    if (kv0 + 64 > kvlen) {
#pragma unroll
      for (int st = 0; st < 4; ++st)
        if (kv0 + st * 16 + r16 >= kvlen) {
#pragma unroll
          for (int qs = 0; qs < 2; ++qs)
#pragma unroll
            for (int rg = 0; rg < 4; ++rg) sa[qs][st][rg] = -3e38f;
        }
    }

    // ---- defer-max check
    float bad = 0.f;
    float m4v[2][4];
#pragma unroll
    for (int qs = 0; qs < 2; ++qs)
#pragma unroll
      for (int rg = 0; rg < 4; ++rg) {
        float m4 = fmaxf(fmaxf(sa[qs][0][rg], sa[qs][1][rg]),
                         fmaxf(sa[qs][2][rg], sa[qs][3][rg]));
        m4v[qs][rg] = m4;
        bad = fmaxf(bad, m4 - mi[qs][rg]);
      }
    if (__any(bad > 16.0f)) {
#pragma unroll
      for (int qs = 0; qs < 2; ++qs)
#pragma unroll
        for (int rg = 0; rg < 4; ++rg) {
          float mx = m4v[qs][rg];
#pragma unroll
          for (int off = 1; off < 16; off <<= 1) mx = fmaxf(mx, __shfl_xor(mx, off));
          const float nm = fmaxf(mi[qs][rg], mx);
          const float corr = __builtin_amdgcn_exp2f((mi[qs][rg] - nm) * C);
          mi[qs][rg] = nm;
          li[qs][rg] *= corr;
#pragma unroll
          for (int ds = 0; ds < 4; ++ds) oacc[qs][ds][rg] *= corr;
        }
    }

    // ---- P = exp, lane-local li accumulate, packed bf16 store
#pragma unroll
    for (int qs = 0; qs < 2; ++qs) {
#pragma unroll
      for (int rg = 0; rg < 4; ++rg) {
        const float mc = mi[qs][rg] * C;
        const float p0 = __builtin_amdgcn_exp2f(__builtin_fmaf(sa[qs][0][rg], C, -mc));
        const float p1 = __builtin_amdgcn_exp2f(__builtin_fmaf(sa[qs][1][rg], C, -mc));
        const float p2 = __builtin_amdgcn_exp2f(__builtin_fmaf(sa[qs][2][rg], C, -mc));
        const float p3 = __builtin_amdgcn_exp2f(__builtin_fmaf(sa[qs][3][rg], C, -mc));
        li[qs][rg] += (p0 + p1) + (p2 + p3);
        unsigned lo, hi;
        asm("v_cvt_pk_bf16_f32 %0, %1, %2" : "=v"(lo) : "v"(p0), "v"(p1));
        asm("v_cvt_pk_bf16_f32 %0, %1, %2" : "=v"(hi) : "v"(p2), "v"(p3));
        const int prow = qs * 16 + g * 4 + rg;
        uint2 pk; pk.x = lo; pk.y = hi;
        *(uint2*)&Ps[wave][prow * 72 + r16 * 4] = pk;
      }
    }

    // ---- PV: 16 MFMA
    __builtin_amdgcn_s_setprio(1);
#pragma unroll
    for (int kc = 0; kc < 2; ++kc) {
      const bf16x8 pa0 = *(const bf16x8*)&Ps[wave][(r16)      * 72 + kc * 32 + g * 8];
      const bf16x8 pa1 = *(const bf16x8*)&Ps[wave][(16 + r16) * 72 + kc * 32 + g * 8];
#pragma unroll
      for (int ds = 0; ds < 4; ++ds) {
        const int dr = ds * 16 + r16;
        const int chs = (kc * 4 + g) ^ (dr & 7);
        const bf16x8 vf = *(const bf16x8*)&Vs[cur][dr * 64 + chs * 8];
        oacc[0][ds] = mfma16(pa0, vf, oacc[0][ds]);
        oacc[1][ds] = mfma16(pa1, vf, oacc[1][ds]);
      }
    }
    __builtin_amdgcn_s_setprio(0);

    __builtin_amdgcn_s_barrier();                        // B2
  }

#pragma unroll
  for (int qs = 0; qs < 2; ++qs)
#pragma unroll
    for (int rg = 0; rg < 4; ++rg) {
      float s = li[qs][rg];
#pragma unroll
      for (int off = 1; off < 16; off <<= 1) s += __shfl_xor(s, off);
      li[qs][rg] = s;
    }

#pragma unroll
  for (int qs = 0; qs < 2; ++qs)
#pragma unroll
    for (int rg = 0; rg < 4; ++rg) {
      const float inv = 1.0f / li[qs][rg];
      const int row = q0 + qs * 16 + g * 4 + rg;
      const size_t base = (size_t)(b * SEQ + row) * DIMN + h * DHEAD;
#pragma unroll
      for (int ds = 0; ds < 4; ++ds)
        o[base + ds * 16 + r16] = f2bf(oacc[qs][ds][rg] * inv);
    }
}

extern "C" void kernel_launch(void* const* d_in, const int* in_sizes, int n_in,
                              void* d_out, int out_size, void* d_ws, size_t ws_size,
                              hipStream_t stream)
{
  const float* x   = (const float*)d_in[0];
  const float* ctx = (const float*)d_in[1];
  const float* Wq1 = (const float*)d_in[2];
  const float* Wk1 = (const float*)d_in[3];
  const float* Wv1 = (const float*)d_in[4];
  const float* Wo1 = (const float*)d_in[5];
  const float* bo1 = (const float*)d_in[6];
  const float* Wq2 = (const float*)d_in[7];
  const float* Wk2 = (const float*)d_in[8];
  const float* Wv2 = (const float*)d_in[9];
  const float* Wo2 = (const float*)d_in[10];
  const float* bo2 = (const float*)d_in[11];
  const float* Wp  = (const float*)d_in[12];
  const float* bp  = (const float*)d_in[13];
  const float* W2  = (const float*)d_in[14];
  const float* b2  = (const float*)d_in[15];
  const float* g1  = (const float*)d_in[16];
  const float* be1 = (const float*)d_in[17];
  const float* g2  = (const float*)d_in[18];
  const float* be2 = (const float*)d_in[19];
  const float* g3  = (const float*)d_in[20];
  const float* be3 = (const float*)d_in[21];

  char* ws = (char*)d_ws;
  size_t off = 0;
  auto alloc = [&](size_t bytes) -> void* {
    void* p = ws + off;
    off += (bytes + 255) & ~(size_t)255;
    return p;
  };

  u16* WqT1 = (u16*)alloc((size_t)1024 * 1024 * 2);   // contiguous with WkT1, WvT1
  u16* WkT1 = (u16*)alloc((size_t)1024 * 1024 * 2);
  u16* WvT1 = (u16*)alloc((size_t)1024 * 1024 * 2);
  u16* WoT1 = (u16*)alloc((size_t)1024 * 1024 * 2);
  u16* WqT2 = (u16*)alloc((size_t)1024 * 1024 * 2);
  u16* WkT2 = (u16*)alloc((size_t)1024 * 768 * 2);    // contiguous with WvT2
  u16* WvT2 = (u16*)alloc((size_t)1024 * 768 * 2);
  u16* WoT2 = (u16*)alloc((size_t)1024 * 1024 * 2);
  u16* WpT  = (u16*)alloc((size_t)8192 * 1024 * 2);
  u16* W2T  = (u16*)alloc((size_t)1024 * 4096 * 2);
  float* x1f = (float*)alloc((size_t)NTOK * DIMN * 4);
  float* x2f = (float*)alloc((size_t)NTOK * DIMN * 4);
  u16* ctxb = (u16*)alloc((size_t)CTOK * CTXD * 2);
  u16* k2b  = (u16*)alloc((size_t)CTOK * DIMN * 2);
  u16* vt2b = (u16*)alloc((size_t)2 * HEADS * DHEAD * 128 * 2);
  u16* hb   = (u16*)alloc((size_t)NTOK * DIMN * 2);
  u16* qb   = (u16*)alloc((size_t)NTOK * DIMN * 2);
  u16* kb   = (u16*)alloc((size_t)NTOK * DIMN * 2);
  u16* vtb  = (u16*)alloc((size_t)NTOK * DIMN * 2);
  u16* ab   = (u16*)alloc((size_t)NTOK * DIMN * 2);
  u16* ub   = qb; // reuse qb..ab region (32MB) for FF intermediate [4096][4096]

  dim3 blk(256);
  dim3 blk5(512);

  // batched weight conversions
  WBatch wb6;
  wb6.s[0] = Wq1; wb6.d[0] = WqT1;
  wb6.s[1] = Wk1; wb6.d[1] = WkT1;
  wb6.s[2] = Wv1; wb6.d[2] = WvT1;
  wb6.s[3] = Wo1; wb6.d[3] = WoT1;
  wb6.s[4] = Wq2; wb6.d[4] = WqT2;
  wb6.s[5] = Wo2; wb6.d[5] = WoT2;
  wconvB_k<6><<<dim3(16, 16, 6), blk, 0, stream>>>(wb6, 1024, 1024);
  WBatch wb2;
  wb2.s[0] = Wk2; wb2.d[0] = WkT2;
  wb2.s[1] = Wv2; wb2.d[1] = WvT2;
  wb2.s[2] = nullptr; wb2.d[2] = nullptr;
  wb2.s[3] = nullptr; wb2.d[3] = nullptr;
  wb2.s[4] = nullptr; wb2.d[4] = nullptr;
  wb2.s[5] = nullptr; wb2.d[5] = nullptr;
  wconvB_k<2><<<dim3(16, 12, 2), blk, 0, stream>>>(wb2, 768, 1024);
  wconv_k<<<dim3(128, 16), blk, 0, stream>>>(Wp, WpT, 1024, 8192);
  wconv_k<<<dim3(16, 64), blk, 0, stream>>>(W2, W2T, 4096, 1024);
  cconv_k<<<dim3((CTOK * CTXD + 255) / 256), blk, 0, stream>>>(ctx, ctxb, CTOK * CTXD);

  // ---- self attention block (QKV fused: WqT1/WkT1/WvT1 contiguous, N=3072)
  ln_k<<<NTOK, 256, 0, stream>>>(x, g1, be1, hb);
  gemm_k<4><<<dim3(32, 24), blk5, 0, stream>>>(hb, WqT1, NTOK, 3072, 1024, nullptr, nullptr, qb, nullptr, SEQ, SEQ, kb, vtb);
  attn_k<<<dim3(16, 32), blk, 0, stream>>>(qb, kb, vtb, ab, SEQ, SEQ, SEQ);
  gemm_k<2><<<dim3(32, 8), blk5, 0, stream>>>(ab, WoT1, NTOK, 1024, 1024, bo1, x, nullptr, x1f, 0, 0, nullptr, nullptr);

  // ---- cross attention block (K2+V2 fused over ctx, N=2048)
  ln_k<<<NTOK, 256, 0, stream>>>(x1f, g2, be2, hb);
  gemm_k<0><<<dim3(32, 8), blk5, 0, stream>>>(hb, WqT2, NTOK, 1024, 1024, nullptr, nullptr, qb, nullptr, 0, 0, nullptr, nullptr);
  gemm_k<5><<<dim3(2, 16), blk5, 0, stream>>>(ctxb, WkT2, CTOK, 2048, 768, nullptr, nullptr, k2b, nullptr, NCTX, 128, nullptr, vt2b);
  attn_k<<<dim3(16, 32), blk, 0, stream>>>(qb, k2b, vt2b, ab, NCTX, NCTX, 128);
  gemm_k<2><<<dim3(32, 8), blk5, 0, stream>>>(ab, WoT2, NTOK, 1024, 1024, bo2, x1f, nullptr, x2f, 0, 0, nullptr, nullptr);

  // ---- GEGLU FF block
  ln_k<<<NTOK, 256, 0, stream>>>(x2f, g3, be3, hb);
  geglu_k<<<dim3(32, 32), blk5, 0, stream>>>(hb, WpT, WpT + (size_t)4096 * 1024, bp, bp + 4096, ub, NTOK, FFH);
  gemm_k<2><<<dim3(32, 8), blk5, 0, stream>>>(ub, W2T, NTOK, 1024, 4096, b2, x2f, nullptr, (float*)d_out, 0, 0, nullptr, nullptr);

  (void)in_sizes; (void)n_in; (void)out_size; (void)ws_size;
}